// Round 1
// 886.569 us; speedup vs baseline: 1.0006x; 1.0006x over previous
//
#include <hip/hip_runtime.h>
#include <math.h>

#define BB 2
#define LL 2048
#define DD 1024
#define HH 16
#define SCALE 0.03125f   // 1/sqrt(1024)

#define ATTN_ELEMS ((size_t)BB * LL * DD)           // 4,194,304 fp32

typedef unsigned short u16;
typedef __attribute__((ext_vector_type(8))) short bf16x8;
typedef __attribute__((ext_vector_type(4))) short s16x4;
typedef __attribute__((ext_vector_type(4))) float f32x4;

__device__ __forceinline__ u16 f2bf_rne(float f) {
    union { float f; unsigned u; } c; c.f = f;
    unsigned u = c.u;
    u += 0x7fffu + ((u >> 16) & 1u);
    return (u16)(u >> 16);
}

// fp32 -> bf16 hi (truncate) + bf16 lo (RNE of residual); x ≈ hi+lo, |err| ≲ 2^-17|x|
__device__ __forceinline__ void splitbf(float x, short& h, short& l) {
    union { float f; unsigned u; } c; c.f = x;
    unsigned uh = c.u & 0xFFFF0000u;
    h = (short)(uh >> 16);
    union { unsigned u; float f; } ch; ch.u = uh;
    l = (short)f2bf_rne(x - ch.f);
}

// Branchless stable insert of (cv,ci) into descending-sorted 8-list.
// Precondition: cv > tv[7]. Candidates arrive in ascending index order.
__device__ __forceinline__ void insert8(float (&tv)[8], int (&ti)[8], float cv, int ci) {
    bool g0 = cv > tv[0], g1 = cv > tv[1], g2 = cv > tv[2], g3 = cv > tv[3],
         g4 = cv > tv[4], g5 = cv > tv[5], g6 = cv > tv[6];
    tv[7] = g6 ? tv[6] : cv;                 ti[7] = g6 ? ti[6] : ci;
    tv[6] = g5 ? tv[5] : (g6 ? cv : tv[6]);  ti[6] = g5 ? ti[5] : (g6 ? ci : ti[6]);
    tv[5] = g4 ? tv[4] : (g5 ? cv : tv[5]);  ti[5] = g4 ? ti[4] : (g5 ? ci : ti[5]);
    tv[4] = g3 ? tv[3] : (g4 ? cv : tv[4]);  ti[4] = g3 ? ti[3] : (g4 ? ci : ti[4]);
    tv[3] = g2 ? tv[2] : (g3 ? cv : tv[3]);  ti[3] = g2 ? ti[2] : (g3 ? ci : ti[3]);
    tv[2] = g1 ? tv[1] : (g2 ? cv : tv[2]);  ti[2] = g1 ? ti[1] : (g2 ? ci : ti[2]);
    tv[1] = g0 ? tv[0] : (g1 ? cv : tv[1]);  ti[1] = g0 ? ti[0] : (g1 ? ci : ti[1]);
    tv[0] = g0 ? cv : tv[0];                 ti[0] = g0 ? ci : ti[0];
}

// Merge four descending-sorted 8-lists -> top-8 (value desc, index asc on ties).
__device__ __forceinline__ void merge4(
    const float* v0, const int* i0, const float* v1, const int* i1,
    const float* v2, const int* i2, const float* v3, const int* i3,
    float* ov, int* oi)
{
    int p0 = 0, p1 = 0, p2 = 0, p3 = 0;
    #pragma unroll
    for (int s = 0; s < 8; ++s) {
        float a0 = v0[p0], a1 = v1[p1], a2 = v2[p2], a3 = v3[p3];
        int   b0 = i0[p0], b1 = i1[p1], b2 = i2[p2], b3 = i3[p3];
        float bv = a0; int bi = b0; int bc = 0;
        if (a1 > bv || (a1 == bv && b1 < bi)) { bv = a1; bi = b1; bc = 1; }
        if (a2 > bv || (a2 == bv && b2 < bi)) { bv = a2; bi = b2; bc = 2; }
        if (a3 > bv || (a3 == bv && b3 < bi)) { bv = a3; bi = b3; bc = 3; }
        p0 += (bc == 0); p1 += (bc == 1); p2 += (bc == 2); p3 += (bc == 3);
        ov[s] = bv; oi[s] = bi;
    }
}

// ===========================================================================
// FAST PATH (ws >= 36 MB)
// ===========================================================================

// K fp32 -> split-bf16, stored in MFMA B-fragment layout per (b,h):
// shorts offset within head = s*1024 + c*512 + qd*128 + li*8  (head stride 131072)
// so that attn fragment load is khi[head_base + s*1024 + c*512 + lane*8].
__global__ __launch_bounds__(256) void prep_k_kernel(
    const float* __restrict__ k, u16* __restrict__ khi, u16* __restrict__ klo)
{
    int gid = blockIdx.x * 256 + threadIdx.x;          // 0 .. 524287
    int li   = gid & 15;
    int qd   = (gid >> 4) & 3;
    int c    = (gid >> 6) & 1;
    int s    = (gid >> 7) & 127;
    int head = gid >> 14;                              // 0 .. 31
    int b = head >> 4, h = head & 15;
    const float* src = k + ((size_t)(b * LL + s * 16 + li)) * DD + h * 64 + c * 32 + qd * 8;
    float x[8];
    *(f32x4*)x       = *(const f32x4*)src;
    *(f32x4*)(x + 4) = *(const f32x4*)(src + 4);
    bf16x8 h8, l8;
    #pragma unroll
    for (int e = 0; e < 8; ++e) { short hh, ll; splitbf(x[e], hh, ll); h8[e] = hh; l8[e] = ll; }
    *(bf16x8*)&khi[(size_t)gid * 8] = h8;
    *(bf16x8*)&klo[(size_t)gid * 8] = l8;
}

// W fp32 -> split-bf16 fragment layout:
// shorts offset = nb*65536 + kc*8192 + nt*2048 + c*512 + qd*128 + li*8
__global__ __launch_bounds__(256) void prep_w_kernel(
    const float* __restrict__ w, u16* __restrict__ whi, u16* __restrict__ wlo)
{
    int gid = blockIdx.x * 256 + threadIdx.x;          // 0 .. 131071
    int li = gid & 15;
    int qd = (gid >> 4) & 3;
    int c  = (gid >> 6) & 3;
    int nt = (gid >> 8) & 3;
    int kc = (gid >> 10) & 7;
    int nb = gid >> 13;                                // 0 .. 15
    const float* src = w + (size_t)(nb * 64 + nt * 16 + li) * DD + kc * 128 + c * 32 + qd * 8;
    float x[8];
    *(f32x4*)x       = *(const f32x4*)src;
    *(f32x4*)(x + 4) = *(const f32x4*)(src + 4);
    bf16x8 h8, l8;
    #pragma unroll
    for (int e = 0; e < 8; ++e) { short hh, ll; splitbf(x[e], hh, ll); h8[e] = hh; l8[e] = ll; }
    *(bf16x8*)&whi[(size_t)gid * 8] = h8;
    *(bf16x8*)&wlo[(size_t)gid * 8] = l8;
}

// Fused attention, fast path: no K staging (direct coalesced global fragment
// loads from pre-split K), no LDS in the score loop, zero-fill interleaved.
// Emits context directly as split-bf16 (chi/clo) for the projection kernel.
__global__ __launch_bounds__(256) void attn_fast_kernel(
    const float* __restrict__ q, const float* __restrict__ k, const float* __restrict__ v,
    const u16* __restrict__ khi_g, const u16* __restrict__ klo_g,
    float* __restrict__ aw, u16* __restrict__ chi, u16* __restrict__ clo)
{
    const int bid  = blockIdx.x;
    const int qt   = bid & 31;
    const int h    = (bid >> 5) & 15;
    const int b    = bid >> 9;
    const int t    = threadIdx.x;
    const int wv   = t >> 6;
    const int lane = t & 63;
    const int li   = lane & 15;
    const int quad = lane >> 4;

    __shared__ float mv[4096];          // 32 rows x 128
    __shared__ int   mi[4096];
    __shared__ float s2v[32][4][8];
    __shared__ int   s2i[32][4][8];
    __shared__ int   cidx[32][12];
    __shared__ float cs[32][12];
    __shared__ float wrow[64][8];
    __shared__ int   wix[64][8];

    f32x4* awz = (f32x4*)(aw + (((size_t)(b * HH + h) * LL) + (size_t)qt * 64) * LL);
    const f32x4 zero4 = {0.f, 0.f, 0.f, 0.f};

    // Q fragments (split-bf16), same as before
    bf16x8 qh0, ql0, qh1, ql1;
    {
        const float* qrow = q + ((size_t)(b * LL + qt * 64 + wv * 16 + li)) * DD + h * 64;
        float x[8];
        *(f32x4*)x       = *(const f32x4*)(qrow + quad * 8);
        *(f32x4*)(x + 4) = *(const f32x4*)(qrow + quad * 8 + 4);
        #pragma unroll
        for (int e = 0; e < 8; ++e) { short hh, ll; splitbf(x[e], hh, ll); qh0[e] = hh; ql0[e] = ll; }
        *(f32x4*)x       = *(const f32x4*)(qrow + 32 + quad * 8);
        *(f32x4*)(x + 4) = *(const f32x4*)(qrow + 32 + quad * 8 + 4);
        #pragma unroll
        for (int e = 0; e < 8; ++e) { short hh, ll; splitbf(x[e], hh, ll); qh1[e] = hh; ql1[e] = ll; }
    }

    float tv[4][8]; int tix[4][8];
    #pragma unroll
    for (int r = 0; r < 4; ++r)
        #pragma unroll
        for (int s = 0; s < 8; ++s) { tv[r][s] = -INFINITY; tix[r][s] = 0; }

    const u16* khb = khi_g + (size_t)(b * HH + h) * 131072 + (size_t)lane * 8;
    const u16* klb = klo_g + (size_t)(b * HH + h) * 131072 + (size_t)lane * 8;

    bf16x8 kh0 = *(const bf16x8*)(khb);
    bf16x8 kh1 = *(const bf16x8*)(khb + 512);
    bf16x8 kl0 = *(const bf16x8*)(klb);
    bf16x8 kl1 = *(const bf16x8*)(klb + 512);

    #pragma unroll 2
    for (int s = 0; s < 128; ++s) {
        const int sn = (s + 1) & 127;     // wraps to 0 on last iter (harmless re-read)
        bf16x8 nh0 = *(const bf16x8*)(khb + (size_t)sn * 1024);
        bf16x8 nh1 = *(const bf16x8*)(khb + (size_t)sn * 1024 + 512);
        bf16x8 nl0 = *(const bf16x8*)(klb + (size_t)sn * 1024);
        bf16x8 nl1 = *(const bf16x8*)(klb + (size_t)sn * 1024 + 512);

        awz[s * 256 + t] = zero4;         // zero-fill rides along at write BW

        // two independent 3-MFMA chains (dims 0-31 / 32-63) to shorten dep chain
        f32x4 c4a = {0.f, 0.f, 0.f, 0.f};
        f32x4 c4b = {0.f, 0.f, 0.f, 0.f};
        c4a = __builtin_amdgcn_mfma_f32_16x16x32_bf16(qh0, kh0, c4a, 0, 0, 0);
        c4b = __builtin_amdgcn_mfma_f32_16x16x32_bf16(qh1, kh1, c4b, 0, 0, 0);
        c4a = __builtin_amdgcn_mfma_f32_16x16x32_bf16(qh0, kl0, c4a, 0, 0, 0);
        c4b = __builtin_amdgcn_mfma_f32_16x16x32_bf16(qh1, kl1, c4b, 0, 0, 0);
        c4a = __builtin_amdgcn_mfma_f32_16x16x32_bf16(ql0, kh0, c4a, 0, 0, 0);
        c4b = __builtin_amdgcn_mfma_f32_16x16x32_bf16(ql1, kh1, c4b, 0, 0, 0);

        int ci = s * 16 + li;
        #pragma unroll
        for (int r = 0; r < 4; ++r) {
            float cv = (c4a[r] + c4b[r]) * SCALE;
            if (cv > tv[r][7]) insert8(tv[r], tix[r], cv, ci);
        }
        kh0 = nh0; kh1 = nh1; kl0 = nl0; kl1 = nl1;
    }

    for (int bb = 0; bb < 2; ++bb) {
        __syncthreads();
        if ((wv >> 1) == bb) {
            int rl0 = (wv & 1) * 16 + quad * 4;
            #pragma unroll
            for (int r = 0; r < 4; ++r) {
                int base = (rl0 + r) * 128 + li * 8;
                #pragma unroll
                for (int s = 0; s < 8; ++s) { mv[base + s] = tv[r][s]; mi[base + s] = tix[r][s]; }
            }
        }
        __syncthreads();
        // stage 1: 128 threads: 4-way merge of 4 streams -> top-8 each
        if (t < 128) {
            int rr = t >> 2, p = t & 3;
            int base = rr * 128 + p * 32;
            merge4(&mv[base], &mi[base], &mv[base + 8], &mi[base + 8],
                   &mv[base + 16], &mi[base + 16], &mv[base + 24], &mi[base + 24],
                   s2v[rr][p], s2i[rr][p]);
        }
        __syncthreads();
        // stage 2: MFMA top-12 candidate indices per row
        if (t < 32) {
            int rr = t;
            int pp[4] = {0, 0, 0, 0};
            #pragma unroll
            for (int s = 0; s < 12; ++s) {
                float bv = -INFINITY; int bi = 0x7fffffff; int bc = 0;
                #pragma unroll
                for (int l = 0; l < 4; ++l) {
                    if (pp[l] < 8) {
                        float hv = s2v[rr][l][pp[l]]; int hi2 = s2i[rr][l][pp[l]];
                        if (hv > bv || (hv == bv && hi2 < bi)) { bv = hv; bi = hi2; bc = l; }
                    }
                }
                pp[bc] += 1;
                cidx[rr][s] = bi;
            }
        }
        __syncthreads();
        // rescore the 12 candidates per row in exact sequential fp32
        for (int task = t; task < 384; task += 256) {
            int row = task / 12, c = task - row * 12;
            const float* qp = q + ((size_t)(b * LL + qt * 64 + bb * 32 + row)) * DD + h * 64;
            const float* kp = k + ((size_t)(b * LL + cidx[row][c])) * DD + h * 64;
            float acc = 0.f;
            for (int d4 = 0; d4 < 16; ++d4) {
                f32x4 qa = *(const f32x4*)(qp + d4 * 4);
                f32x4 ka = *(const f32x4*)(kp + d4 * 4);
                acc = fmaf(qa[0], ka[0], acc);
                acc = fmaf(qa[1], ka[1], acc);
                acc = fmaf(qa[2], ka[2], acc);
                acc = fmaf(qa[3], ka[3], acc);
            }
            cs[row][c] = acc * SCALE;
        }
        __syncthreads();
        // final top-8 (fp32 desc, index asc), softmax, scatter
        if (t < 32) {
            int rr = t;
            float vv[12]; int ii[12];
            #pragma unroll
            for (int c = 0; c < 12; ++c) { vv[c] = cs[rr][c]; ii[c] = cidx[rr][c]; }
            float fv[8]; int fi[8];
            #pragma unroll
            for (int s = 0; s < 8; ++s) {
                float bv = -INFINITY; int bi = 0x7fffffff; int bc = 0;
                #pragma unroll
                for (int c = 0; c < 12; ++c) {
                    if (vv[c] > bv || (vv[c] == bv && ii[c] < bi)) { bv = vv[c]; bi = ii[c]; bc = c; }
                }
                vv[bc] = -INFINITY;
                fv[s] = bv; fi[s] = bi;
            }
            float m = fv[0];
            float e0[8]; float sum = 0.f;
            #pragma unroll
            for (int s = 0; s < 8; ++s) { e0[s] = __expf(fv[s] - m); sum += e0[s]; }
            float inv = 1.0f / sum;
            int grow = bb * 32 + rr;
            float* awrow = aw + (((size_t)(b * HH + h) * LL) + (size_t)qt * 64 + grow) * LL;
            #pragma unroll
            for (int s = 0; s < 8; ++s) {
                float w8 = e0[s] * inv;
                awrow[fi[s]] = w8;
                wrow[grow][s] = w8; wix[grow][s] = fi[s];
            }
        }
    }
    __syncthreads();

    // context = P @ V; emit split-bf16 directly (identical shorts to what the
    // projection kernel would have computed from fp32 ctx).
    const float* vbase = v + ((size_t)b * LL) * DD + h * 64;
    #pragma unroll
    for (int i = 0; i < 4; ++i) {
        int id = i * 256 + t;
        int row = id >> 4, seg = id & 15;
        f32x4 acc = {0.f, 0.f, 0.f, 0.f};
        #pragma unroll
        for (int s = 0; s < 8; ++s) {
            float ws = wrow[row][s];
            f32x4 vvv = *(const f32x4*)(vbase + (size_t)wix[row][s] * DD + seg * 4);
            acc[0] = fmaf(ws, vvv[0], acc[0]);
            acc[1] = fmaf(ws, vvv[1], acc[1]);
            acc[2] = fmaf(ws, vvv[2], acc[2]);
            acc[3] = fmaf(ws, vvv[3], acc[3]);
        }
        size_t off = ((size_t)(b * LL + qt * 64 + row)) * DD + h * 64 + seg * 4;
        s16x4 h4, l4;
        #pragma unroll
        for (int j = 0; j < 4; ++j) { short hh, ll; splitbf(acc[j], hh, ll); h4[j] = hh; l4[j] = ll; }
        *(s16x4*)(chi + off) = h4;
        *(s16x4*)(clo + off) = l4;
    }
}

// Projection, fast path: A (ctx) and B (w) both pre-split; pure load + MFMA.
// No LDS, no barriers, no conversions. Same accumulation order as linear_ws.
__global__ __launch_bounds__(256) void linear_fast_kernel(
    const u16* __restrict__ chi, const u16* __restrict__ clo,
    const u16* __restrict__ whi, const u16* __restrict__ wlo,
    const float* __restrict__ bias, float* __restrict__ out)
{
    const int bid  = blockIdx.x;
    const int nb   = bid & 15, mb = bid >> 4;
    const int t    = threadIdx.x;
    const int wv   = t >> 6;
    const int lane = t & 63;
    const int li   = lane & 15;
    const int quad = lane >> 4;

    f32x4 acc0 = {0.f,0.f,0.f,0.f}, acc1 = {0.f,0.f,0.f,0.f},
          acc2 = {0.f,0.f,0.f,0.f}, acc3 = {0.f,0.f,0.f,0.f};

    const u16* ah_row = chi + (size_t)(mb * 64 + wv * 16 + li) * DD + quad * 8;
    const u16* al_row = clo + (size_t)(mb * 64 + wv * 16 + li) * DD + quad * 8;
    const size_t wboff = (size_t)nb * 65536 + (size_t)lane * 8;

    for (int kc = 0; kc < 8; ++kc) {
        const u16* wb_h = whi + wboff + kc * 8192;
        const u16* wb_l = wlo + wboff + kc * 8192;
        #pragma unroll
        for (int c = 0; c < 4; ++c) {
            bf16x8 ah = *(const bf16x8*)(ah_row + kc * 128 + c * 32);
            bf16x8 al = *(const bf16x8*)(al_row + kc * 128 + c * 32);
            bf16x8 bh0 = *(const bf16x8*)(wb_h + c * 512);
            bf16x8 bl0 = *(const bf16x8*)(wb_l + c * 512);
            bf16x8 bh1 = *(const bf16x8*)(wb_h + 2048 + c * 512);
            bf16x8 bl1 = *(const bf16x8*)(wb_l + 2048 + c * 512);
            bf16x8 bh2 = *(const bf16x8*)(wb_h + 4096 + c * 512);
            bf16x8 bl2 = *(const bf16x8*)(wb_l + 4096 + c * 512);
            bf16x8 bh3 = *(const bf16x8*)(wb_h + 6144 + c * 512);
            bf16x8 bl3 = *(const bf16x8*)(wb_l + 6144 + c * 512);
            acc0 = __builtin_amdgcn_mfma_f32_16x16x32_bf16(ah, bh0, acc0, 0, 0, 0);
            acc0 = __builtin_amdgcn_mfma_f32_16x16x32_bf16(ah, bl0, acc0, 0, 0, 0);
            acc0 = __builtin_amdgcn_mfma_f32_16x16x32_bf16(al, bh0, acc0, 0, 0, 0);
            acc1 = __builtin_amdgcn_mfma_f32_16x16x32_bf16(ah, bh1, acc1, 0, 0, 0);
            acc1 = __builtin_amdgcn_mfma_f32_16x16x32_bf16(ah, bl1, acc1, 0, 0, 0);
            acc1 = __builtin_amdgcn_mfma_f32_16x16x32_bf16(al, bh1, acc1, 0, 0, 0);
            acc2 = __builtin_amdgcn_mfma_f32_16x16x32_bf16(ah, bh2, acc2, 0, 0, 0);
            acc2 = __builtin_amdgcn_mfma_f32_16x16x32_bf16(ah, bl2, acc2, 0, 0, 0);
            acc2 = __builtin_amdgcn_mfma_f32_16x16x32_bf16(al, bh2, acc2, 0, 0, 0);
            acc3 = __builtin_amdgcn_mfma_f32_16x16x32_bf16(ah, bh3, acc3, 0, 0, 0);
            acc3 = __builtin_amdgcn_mfma_f32_16x16x32_bf16(ah, bl3, acc3, 0, 0, 0);
            acc3 = __builtin_amdgcn_mfma_f32_16x16x32_bf16(al, bh3, acc3, 0, 0, 0);
        }
    }

    #pragma unroll
    for (int st = 0; st < 4; ++st) {
        f32x4 a = (st == 0) ? acc0 : (st == 1) ? acc1 : (st == 2) ? acc2 : acc3;
        int col = nb * 64 + st * 16 + li;
        float bb2 = bias[col];
        #pragma unroll
        for (int r = 0; r < 4; ++r)
            out[(size_t)(mb * 64 + wv * 16 + quad * 4 + r) * DD + col] = a[r] + bb2;
    }
}

// ===========================================================================
// FALLBACK PATH (unchanged from previous passing version)
// ===========================================================================

__global__ __launch_bounds__(256) void attn_kernel(
    const float* __restrict__ q, const float* __restrict__ k, const float* __restrict__ v,
    float* __restrict__ aw, float* __restrict__ ctx)
{
    const int bid  = blockIdx.x;
    const int qt   = bid & 31;
    const int h    = (bid >> 5) & 15;
    const int b    = bid >> 9;
    const int t    = threadIdx.x;
    const int wv   = t >> 6;
    const int lane = t & 63;
    const int li   = lane & 15;
    const int quad = lane >> 4;

    __shared__ __align__(16) char smA[32768];
    __shared__ float s2v[32][4][8];
    __shared__ int   s2i[32][4][8];
    __shared__ int   cidx[32][12];
    __shared__ float cs[32][12];
    __shared__ float wrow[64][8];
    __shared__ int   wix[64][8];
    u16* khi = (u16*)smA;
    u16* klo = (u16*)(smA + 16384);

    const float* kbase = k + ((size_t)b * LL) * DD + h * 64;
    f32x4* awz = (f32x4*)(aw + (((size_t)(b * HH + h) * LL) + (size_t)qt * 64) * LL);
    const f32x4 zero4 = {0.f, 0.f, 0.f, 0.f};

    bf16x8 qh0, ql0, qh1, ql1;
    {
        const float* qrow = q + ((size_t)(b * LL + qt * 64 + wv * 16 + li)) * DD + h * 64;
        float x[8];
        *(f32x4*)x       = *(const f32x4*)(qrow + quad * 8);
        *(f32x4*)(x + 4) = *(const f32x4*)(qrow + quad * 8 + 4);
        #pragma unroll
        for (int e = 0; e < 8; ++e) { short hh, ll; splitbf(x[e], hh, ll); qh0[e] = hh; ql0[e] = ll; }
        *(f32x4*)x       = *(const f32x4*)(qrow + 32 + quad * 8);
        *(f32x4*)(x + 4) = *(const f32x4*)(qrow + 32 + quad * 8 + 4);
        #pragma unroll
        for (int e = 0; e < 8; ++e) { short hh, ll; splitbf(x[e], hh, ll); qh1[e] = hh; ql1[e] = ll; }
    }

    float tv[4][8]; int tix[4][8];
    #pragma unroll
    for (int r = 0; r < 4; ++r)
        #pragma unroll
        for (int s = 0; s < 8; ++s) { tv[r][s] = -INFINITY; tix[r][s] = 0; }

    for (int iter = 0; iter < 16; ++iter) {
        __syncthreads();
        #pragma unroll
        for (int j = 0; j < 4; ++j) {
            int f   = j * 256 + t;
            int col = f >> 3;
            int c   = (f >> 2) & 1;
            int qd  = f & 3;
            const float* src = kbase + (size_t)(iter * 128 + col) * DD + c * 32 + qd * 8;
            float x[8];
            *(f32x4*)x       = *(const f32x4*)src;
            *(f32x4*)(x + 4) = *(const f32x4*)(src + 4);
            bf16x8 h8, l8;
            #pragma unroll
            for (int e = 0; e < 8; ++e) { short hh, ll; splitbf(x[e], hh, ll); h8[e] = hh; l8[e] = ll; }
            int off = (((col >> 4) * 2 + c) << 9) + (qd << 7) + ((col & 15) << 3);
            *(bf16x8*)&khi[off] = h8;
            *(bf16x8*)&klo[off] = l8;
        }
        #pragma unroll
        for (int i = 0; i < 8; ++i) awz[iter * 2048 + i * 256 + t] = zero4;
        __syncthreads();

        #pragma unroll
        for (int s = 0; s < 8; ++s) {
            int fo = s << 10;
            bf16x8 kh0 = *(bf16x8*)&khi[fo + (lane << 3)];
            bf16x8 kh1 = *(bf16x8*)&khi[fo + 512 + (lane << 3)];
            bf16x8 kl0 = *(bf16x8*)&klo[fo + (lane << 3)];
            bf16x8 kl1 = *(bf16x8*)&klo[fo + 512 + (lane << 3)];
            f32x4 c4 = {0.f, 0.f, 0.f, 0.f};
            c4 = __builtin_amdgcn_mfma_f32_16x16x32_bf16(qh0, kh0, c4, 0, 0, 0);
            c4 = __builtin_amdgcn_mfma_f32_16x16x32_bf16(qh1, kh1, c4, 0, 0, 0);
            c4 = __builtin_amdgcn_mfma_f32_16x16x32_bf16(qh0, kl0, c4, 0, 0, 0);
            c4 = __builtin_amdgcn_mfma_f32_16x16x32_bf16(qh1, kl1, c4, 0, 0, 0);
            c4 = __builtin_amdgcn_mfma_f32_16x16x32_bf16(ql0, kh0, c4, 0, 0, 0);
            c4 = __builtin_amdgcn_mfma_f32_16x16x32_bf16(ql1, kh1, c4, 0, 0, 0);
            int ci = iter * 128 + s * 16 + li;
            #pragma unroll
            for (int r = 0; r < 4; ++r) {
                float cv = c4[r] * SCALE;
                if (cv > tv[r][7]) insert8(tv[r], tix[r], cv, ci);
            }
        }
    }

    float* mv = (float*)smA;
    int*   mi = (int*)(smA + 16384);
    for (int bb = 0; bb < 2; ++bb) {
        __syncthreads();
        if ((wv >> 1) == bb) {
            int rl0 = (wv & 1) * 16 + quad * 4;
            #pragma unroll
            for (int r = 0; r < 4; ++r) {
                int base = (rl0 + r) * 128 + li * 8;
                #pragma unroll
                for (int s = 0; s < 8; ++s) { mv[base + s] = tv[r][s]; mi[base + s] = tix[r][s]; }
            }
        }
        __syncthreads();
        if (t < 128) {
            int rr = t >> 2, p = t & 3;
            int base = rr * 128 + p * 32;
            merge4(&mv[base], &mi[base], &mv[base + 8], &mi[base + 8],
                   &mv[base + 16], &mi[base + 16], &mv[base + 24], &mi[base + 24],
                   s2v[rr][p], s2i[rr][p]);
        }
        __syncthreads();
        if (t < 32) {
            int rr = t;
            int pp[4] = {0, 0, 0, 0};
            #pragma unroll
            for (int s = 0; s < 12; ++s) {
                float bv = -INFINITY; int bi = 0x7fffffff; int bc = 0;
                #pragma unroll
                for (int l = 0; l < 4; ++l) {
                    if (pp[l] < 8) {
                        float hv = s2v[rr][l][pp[l]]; int hi2 = s2i[rr][l][pp[l]];
                        if (hv > bv || (hv == bv && hi2 < bi)) { bv = hv; bi = hi2; bc = l; }
                    }
                }
                pp[bc] += 1;
                cidx[rr][s] = bi;
            }
        }
        __syncthreads();
        for (int task = t; task < 384; task += 256) {
            int row = task / 12, c = task - row * 12;
            const float* qp = q + ((size_t)(b * LL + qt * 64 + bb * 32 + row)) * DD + h * 64;
            const float* kp = k + ((size_t)(b * LL + cidx[row][c])) * DD + h * 64;
            float acc = 0.f;
            for (int d4 = 0; d4 < 16; ++d4) {
                f32x4 qa = *(const f32x4*)(qp + d4 * 4);
                f32x4 ka = *(const f32x4*)(kp + d4 * 4);
                acc = fmaf(qa[0], ka[0], acc);
                acc = fmaf(qa[1], ka[1], acc);
                acc = fmaf(qa[2], ka[2], acc);
                acc = fmaf(qa[3], ka[3], acc);
            }
            cs[row][c] = acc * SCALE;
        }
        __syncthreads();
        if (t < 32) {
            int rr = t;
            float vv[12]; int ii[12];
            #pragma unroll
            for (int c = 0; c < 12; ++c) { vv[c] = cs[rr][c]; ii[c] = cidx[rr][c]; }
            float fv[8]; int fi[8];
            #pragma unroll
            for (int s = 0; s < 8; ++s) {
                float bv = -INFINITY; int bi = 0x7fffffff; int bc = 0;
                #pragma unroll
                for (int c = 0; c < 12; ++c) {
                    if (vv[c] > bv || (vv[c] == bv && ii[c] < bi)) { bv = vv[c]; bi = ii[c]; bc = c; }
                }
                vv[bc] = -INFINITY;
                fv[s] = bv; fi[s] = bi;
            }
            float m = fv[0];
            float e0[8]; float sum = 0.f;
            #pragma unroll
            for (int s = 0; s < 8; ++s) { e0[s] = __expf(fv[s] - m); sum += e0[s]; }
            float inv = 1.0f / sum;
            int grow = bb * 32 + rr;
            float* awrow = aw + (((size_t)(b * HH + h) * LL) + (size_t)qt * 64 + grow) * LL;
            #pragma unroll
            for (int s = 0; s < 8; ++s) {
                float w8 = e0[s] * inv;
                awrow[fi[s]] = w8;
                wrow[grow][s] = w8; wix[grow][s] = fi[s];
            }
        }
    }
    __syncthreads();

    const float* vbase = v + ((size_t)b * LL) * DD + h * 64;
    #pragma unroll
    for (int i = 0; i < 4; ++i) {
        int id = i * 256 + t;
        int row = id >> 4, seg = id & 15;
        f32x4 acc = {0.f, 0.f, 0.f, 0.f};
        #pragma unroll
        for (int s = 0; s < 8; ++s) {
            float ws = wrow[row][s];
            f32x4 vvv = *(const f32x4*)(vbase + (size_t)wix[row][s] * DD + seg * 4);
            acc[0] = fmaf(ws, vvv[0], acc[0]);
            acc[1] = fmaf(ws, vvv[1], acc[1]);
            acc[2] = fmaf(ws, vvv[2], acc[2]);
            acc[3] = fmaf(ws, vvv[3], acc[3]);
        }
        *(f32x4*)(ctx + ((size_t)(b * LL + qt * 64 + row)) * DD + h * 64 + seg * 4) = acc;
    }
}

__global__ __launch_bounds__(256) void linear_ws_kernel(
    const float* __restrict__ ctx, const float* __restrict__ w,
    const float* __restrict__ bias, float* __restrict__ out)
{
    const int bid  = blockIdx.x;
    const int nb   = bid & 15, mb = bid >> 4;
    const int t    = threadIdx.x;
    const int wv   = t >> 6;
    const int lane = t & 63;
    const int li   = lane & 15;
    const int quad = lane >> 4;

    __shared__ u16 bhi[8192], blo[8192];

    f32x4 acc0 = {0.f,0.f,0.f,0.f}, acc1 = {0.f,0.f,0.f,0.f},
          acc2 = {0.f,0.f,0.f,0.f}, acc3 = {0.f,0.f,0.f,0.f};
    const float* arow = ctx + (size_t)(mb * 64 + wv * 16 + li) * DD;

    for (int kc = 0; kc < 8; ++kc) {
        __syncthreads();
        #pragma unroll
        for (int j = 0; j < 4; ++j) {
            int f   = j * 256 + t;
            int col = f >> 4;
            int c   = (f >> 2) & 3;
            int qd  = f & 3;
            const float* src = w + (size_t)(nb * 64 + col) * DD + kc * 128 + c * 32 + qd * 8;
            float x[8];
            *(f32x4*)x       = *(const f32x4*)src;
            *(f32x4*)(x + 4) = *(const f32x4*)(src + 4);
            bf16x8 h8, l8;
            #pragma unroll
            for (int e = 0; e < 8; ++e) { short hh, ll; splitbf(x[e], hh, ll); h8[e] = hh; l8[e] = ll; }
            int off = (((col >> 4) * 4 + c) << 9) + (qd << 7) + ((col & 15) << 3);
            *(bf16x8*)&bhi[off] = h8;
            *(bf16x8*)&blo[off] = l8;
        }
        __syncthreads();

        bf16x8 ah[4], al[4];
        #pragma unroll
        for (int c = 0; c < 4; ++c) {
            float x[8];
            *(f32x4*)x       = *(const f32x4*)(arow + kc * 128 + c * 32 + quad * 8);
            *(f32x4*)(x + 4) = *(const f32x4*)(arow + kc * 128 + c * 32 + quad * 8 + 4);
            #pragma unroll
            for (int e = 0; e < 8; ++e) { short hh, ll; splitbf(x[e], hh, ll); ah[c][e] = hh; al[c][e] = ll; }
        }
        #pragma unroll
        for (int c = 0; c < 4; ++c) {
            bf16x8 bh0 = *(bf16x8*)&bhi[(( 0 + c) << 9) + (lane << 3)];
            bf16x8 bl0 = *(bf16x8*)&blo[(( 0 + c) << 9) + (lane << 3)];
            bf16x8 bh1 = *(bf16x8*)&bhi[(( 4 + c) << 9) + (lane << 3)];
            bf16x8 bl1 = *(bf16x8*)&blo[(( 4 + c) << 9) + (lane << 3)];
            bf16x8 bh2 = *(bf16x8*)&bhi[(( 8 + c) << 9) + (lane << 3)];
            bf16x8 bl2 = *(bf16x8*)&blo[(( 8 + c) << 9) + (lane << 3)];
            bf16x8 bh3 = *(bf16x8*)&bhi[((12 + c) << 9) + (lane << 3)];
            bf16x8 bl3 = *(bf16x8*)&blo[((12 + c) << 9) + (lane << 3)];
            acc0 = __builtin_amdgcn_mfma_f32_16x16x32_bf16(ah[c], bh0, acc0, 0, 0, 0);
            acc0 = __builtin_amdgcn_mfma_f32_16x16x32_bf16(ah[c], bl0, acc0, 0, 0, 0);
            acc0 = __builtin_amdgcn_mfma_f32_16x16x32_bf16(al[c], bh0, acc0, 0, 0, 0);
            acc1 = __builtin_amdgcn_mfma_f32_16x16x32_bf16(ah[c], bh1, acc1, 0, 0, 0);
            acc1 = __builtin_amdgcn_mfma_f32_16x16x32_bf16(ah[c], bl1, acc1, 0, 0, 0);
            acc1 = __builtin_amdgcn_mfma_f32_16x16x32_bf16(al[c], bh1, acc1, 0, 0, 0);
            acc2 = __builtin_amdgcn_mfma_f32_16x16x32_bf16(ah[c], bh2, acc2, 0, 0, 0);
            acc2 = __builtin_amdgcn_mfma_f32_16x16x32_bf16(ah[c], bl2, acc2, 0, 0, 0);
            acc2 = __builtin_amdgcn_mfma_f32_16x16x32_bf16(al[c], bh2, acc2, 0, 0, 0);
            acc3 = __builtin_amdgcn_mfma_f32_16x16x32_bf16(ah[c], bh3, acc3, 0, 0, 0);
            acc3 = __builtin_amdgcn_mfma_f32_16x16x32_bf16(ah[c], bl3, acc3, 0, 0, 0);
            acc3 = __builtin_amdgcn_mfma_f32_16x16x32_bf16(al[c], bh3, acc3, 0, 0, 0);
        }
    }

    #pragma unroll
    for (int st = 0; st < 4; ++st) {
        f32x4 a = (st == 0) ? acc0 : (st == 1) ? acc1 : (st == 2) ? acc2 : acc3;
        int col = nb * 64 + st * 16 + li;
        float bb2 = bias[col];
        #pragma unroll
        for (int r = 0; r < 4; ++r)
            out[(size_t)(mb * 64 + wv * 16 + quad * 4 + r) * DD + col] = a[r] + bb2;
    }
}

__global__ __launch_bounds__(256) void linear_inplace_kernel(
    float* io, const float* __restrict__ w, const float* __restrict__ bias)
{
    __shared__ u16 ahi[16384], alo[16384];
    const int t    = threadIdx.x;
    const int m0   = blockIdx.x * 16;
    const int wv   = t >> 6;
    const int lane = t & 63;
    const int li   = lane & 15;
    const int quad = lane >> 4;

    #pragma unroll
    for (int i = 0; i < 8; ++i) {
        int id  = i * 256 + t;
        int row = id >> 7;
        int c   = (id >> 2) & 31;
        int qd  = id & 3;
        const float* src = io + (size_t)(m0 + row) * DD + c * 32 + qd * 8;
        float x[8];
        *(f32x4*)x       = *(const f32x4*)src;
        *(f32x4*)(x + 4) = *(const f32x4*)(src + 4);
        bf16x8 h8, l8;
        #pragma unroll
        for (int e = 0; e < 8; ++e) { short hh, ll; splitbf(x[e], hh, ll); h8[e] = hh; l8[e] = ll; }
        int off = (c << 9) + (qd << 7) + (row << 3);
        *(bf16x8*)&ahi[off] = h8;
        *(bf16x8*)&alo[off] = l8;
    }
    __syncthreads();

    f32x4 acc[16];
    #pragma unroll
    for (int i = 0; i < 16; ++i) acc[i] = (f32x4){0.f, 0.f, 0.f, 0.f};

    for (int c = 0; c < 32; ++c) {
        bf16x8 ah = *(bf16x8*)&ahi[(c << 9) + (lane << 3)];
        bf16x8 al = *(bf16x8*)&alo[(c << 9) + (lane << 3)];
        #pragma unroll
        for (int sub = 0; sub < 16; ++sub) {
            int col = wv * 256 + sub * 16 + li;
            const float* src = w + (size_t)col * DD + c * 32 + quad * 8;
            float x[8];
            *(f32x4*)x       = *(const f32x4*)src;
            *(f32x4*)(x + 4) = *(const f32x4*)(src + 4);
            bf16x8 bh, bl;
            #pragma unroll
            for (int e = 0; e < 8; ++e) { short hh, ll; splitbf(x[e], hh, ll); bh[e] = hh; bl[e] = ll; }
            acc[sub] = __builtin_amdgcn_mfma_f32_16x16x32_bf16(ah, bh, acc[sub], 0, 0, 0);
            acc[sub] = __builtin_amdgcn_mfma_f32_16x16x32_bf16(ah, bl, acc[sub], 0, 0, 0);
            acc[sub] = __builtin_amdgcn_mfma_f32_16x16x32_bf16(al, bh, acc[sub], 0, 0, 0);
        }
    }

    #pragma unroll
    for (int sub = 0; sub < 16; ++sub) {
        int col = wv * 256 + sub * 16 + li;
        float bb2 = bias[col];
        #pragma unroll
        for (int r = 0; r < 4; ++r)
            io[(size_t)(m0 + quad * 4 + r) * DD + col] = acc[sub][r] + bb2;
    }
}

extern "C" void kernel_launch(void* const* d_in, const int* in_sizes, int n_in,
                              void* d_out, int out_size, void* d_ws, size_t ws_size,
                              hipStream_t stream) {
    const float* q    = (const float*)d_in[0];
    const float* k    = (const float*)d_in[1];
    const float* v    = (const float*)d_in[2];
    const float* w    = (const float*)d_in[3];
    const float* bias = (const float*)d_in[4];

    float* out = (float*)d_out;                  // attn_out [B*L*D]
    float* aw  = out + ATTN_ELEMS;               // attn_weights [B*H*L*L]

    const size_t CHI_ELE = ATTN_ELEMS;           // shorts (ctx split)
    const size_t KSP_ELE = 4194304;              // shorts (k split, fragment layout)
    const size_t WSP_ELE = 1048576;              // shorts (w split, fragment layout)
    const size_t need_fast = (2 * CHI_ELE + 2 * KSP_ELE + 2 * WSP_ELE) * sizeof(u16); // 36 MB

    if (d_ws != nullptr && ws_size >= need_fast) {
        u16* chi = (u16*)d_ws;
        u16* clo = chi + CHI_ELE;
        u16* khi = clo + CHI_ELE;
        u16* klo = khi + KSP_ELE;
        u16* whi = klo + KSP_ELE;
        u16* wlo = whi + WSP_ELE;
        prep_k_kernel<<<2048, 256, 0, stream>>>(k, khi, klo);
        prep_w_kernel<<<512, 256, 0, stream>>>(w, whi, wlo);
        attn_fast_kernel<<<BB * HH * (LL / 64), 256, 0, stream>>>(q, k, v, khi, klo, aw, chi, clo);
        linear_fast_kernel<<<(BB * LL / 64) * (DD / 64), 256, 0, stream>>>(chi, clo, whi, wlo, bias, out);
    } else {
        const bool use_ws = (d_ws != nullptr) && (ws_size >= ATTN_ELEMS * sizeof(float));
        float* ctx = use_ws ? (float*)d_ws : out;
        attn_kernel<<<BB * HH * (LL / 64), 256, 0, stream>>>(q, k, v, aw, ctx);
        if (use_ws) {
            linear_ws_kernel<<<(BB * LL / 64) * (DD / 64), 256, 0, stream>>>(ctx, w, bias, out);
        } else {
            linear_inplace_kernel<<<BB * LL / 16, 256, 0, stream>>>(out, w, bias);
        }
    }
}